// Round 1
// baseline (587.075 us; speedup 1.0000x reference)
//
#include <hip/hip_runtime.h>

typedef __attribute__((ext_vector_type(8))) short s16x8;
typedef __attribute__((ext_vector_type(8))) unsigned short u16x8;
typedef __attribute__((ext_vector_type(4))) unsigned short u16x4;
typedef __attribute__((ext_vector_type(4))) float f32x4;

__device__ __forceinline__ unsigned short f2bf(float f) {
  union { float f; unsigned int u; } v; v.f = f;
  unsigned int r = (v.u + 0x7FFFu + ((v.u >> 16) & 1u)) >> 16;
  return (unsigned short)r;
}
__device__ __forceinline__ float bf2f(unsigned short h) {
  union { unsigned int u; float f; } v; v.u = ((unsigned int)h) << 16;
  return v.f;
}
__device__ __forceinline__ float gelu(float x) {
  return 0.5f * x * (1.f + erff(x * 0.70710678118654752f));
}

__device__ __forceinline__ void gld16(const void* g, void* l) {
  __builtin_amdgcn_global_load_lds(
      (const __attribute__((address_space(1))) unsigned int*)g,
      (__attribute__((address_space(3))) unsigned int*)l, 16, 0, 0);
}

__device__ __forceinline__ float blk_sum(float v, float* red, int tid, int nw) {
#pragma unroll
  for (int m = 32; m >= 1; m >>= 1) v += __shfl_xor(v, m);
  __syncthreads();
  if ((tid & 63) == 0) red[tid >> 6] = v;
  __syncthreads();
  float t = 0.f;
  for (int i = 0; i < nw; ++i) t += red[i];
  return t;
}

// ---------------- weight prep ----------------
// W logical [H][D][DH] fp32 -> Wt bf16 [(h*DH+dh)][d] (i.e. [N][K])
__global__ __launch_bounds__(256) void k_transpose(
    const float* __restrict__ W, unsigned short* __restrict__ Wt,
    int D, int DH, int total) {
  int idx = blockIdx.x * 256 + threadIdx.x;
  if (idx >= total) return;
  int dh = idx % DH;
  int r = idx / DH;
  int d = r % D;
  int h = r / D;
  Wt[((size_t)(h * DH + dh)) * D + d] = f2bf(W[idx]);
}

__global__ __launch_bounds__(256) void k_bias3(
    const float* __restrict__ a, const float* __restrict__ b,
    const float* __restrict__ c, float* __restrict__ o) {
  int i = blockIdx.x * 256 + threadIdx.x;
  if (i >= 3072) return;
  o[i] = (i < 1024) ? a[i] : ((i < 2048) ? b[i - 1024] : c[i - 2048]);
}

// ---------------- layernorm kernels ----------------
__global__ __launch_bounds__(256) void k_pre_ln(
    const float* __restrict__ X, const float* __restrict__ g,
    const float* __restrict__ bta, unsigned short* __restrict__ out) {
  __shared__ float red[4];
  const int row = blockIdx.x, tid = threadIdx.x;
  const f32x4 x = *(const f32x4*)(X + (size_t)row * 1024 + tid * 4);
  float s = x[0] + x[1] + x[2] + x[3];
  s = blk_sum(s, red, tid, 4);
  const float mean = s * (1.f / 1024.f);
  f32x4 d;
#pragma unroll
  for (int i = 0; i < 4; ++i) d[i] = x[i] - mean;
  float sq = d[0] * d[0] + d[1] * d[1] + d[2] * d[2] + d[3] * d[3];
  sq = blk_sum(sq, red, tid, 4);
  const float rstd = rsqrtf(sq * (1.f / 1024.f) + 1e-5f);
  const f32x4 gv = *(const f32x4*)(g + tid * 4);
  const f32x4 bv = *(const f32x4*)(bta + tid * 4);
  u16x4 o;
#pragma unroll
  for (int i = 0; i < 4; ++i) o[i] = f2bf(d[i] * rstd * gv[i] + bv[i]);
  *(u16x4*)(out + (size_t)row * 1024 + tid * 4) = o;
}

// X1 = X + attn ; t2 = LN(X1)*g+b  (X1 written to io = d_out)
__global__ __launch_bounds__(256) void k_res_ln(
    const float* __restrict__ X, const unsigned short* __restrict__ attn,
    const float* __restrict__ g, const float* __restrict__ bta,
    float* __restrict__ X1, unsigned short* __restrict__ t2) {
  __shared__ float red[4];
  const int row = blockIdx.x, tid = threadIdx.x;
  const f32x4 x = *(const f32x4*)(X + (size_t)row * 1024 + tid * 4);
  const u16x4 a = *(const u16x4*)(attn + (size_t)row * 1024 + tid * 4);
  f32x4 x1;
#pragma unroll
  for (int i = 0; i < 4; ++i) x1[i] = x[i] + bf2f(a[i]);
  *(f32x4*)(X1 + (size_t)row * 1024 + tid * 4) = x1;
  float s = x1[0] + x1[1] + x1[2] + x1[3];
  s = blk_sum(s, red, tid, 4);
  const float mean = s * (1.f / 1024.f);
  f32x4 d;
#pragma unroll
  for (int i = 0; i < 4; ++i) d[i] = x1[i] - mean;
  float sq = d[0] * d[0] + d[1] * d[1] + d[2] * d[2] + d[3] * d[3];
  sq = blk_sum(sq, red, tid, 4);
  const float rstd = rsqrtf(sq * (1.f / 1024.f) + 1e-5f);
  const f32x4 gv = *(const f32x4*)(g + tid * 4);
  const f32x4 bv = *(const f32x4*)(bta + tid * 4);
  u16x4 o;
#pragma unroll
  for (int i = 0; i < 4; ++i) o[i] = f2bf(d[i] * rstd * gv[i] + bv[i]);
  *(u16x4*)(t2 + (size_t)row * 1024 + tid * 4) = o;
}

// LN(in)*g+b then GELU, rows of 2048, bf16 in/out
__global__ __launch_bounds__(256) void k_ln_gelu(
    const unsigned short* __restrict__ in, const float* __restrict__ g,
    const float* __restrict__ bta, unsigned short* __restrict__ out) {
  __shared__ float red[4];
  const int row = blockIdx.x, tid = threadIdx.x;
  const u16x8 iv = *(const u16x8*)(in + (size_t)row * 2048 + tid * 8);
  float v[8];
  float s = 0.f;
#pragma unroll
  for (int i = 0; i < 8; ++i) { v[i] = bf2f(iv[i]); s += v[i]; }
  s = blk_sum(s, red, tid, 4);
  const float mean = s * (1.f / 2048.f);
  float sq = 0.f;
#pragma unroll
  for (int i = 0; i < 8; ++i) { v[i] -= mean; sq += v[i] * v[i]; }
  sq = blk_sum(sq, red, tid, 4);
  const float rstd = rsqrtf(sq * (1.f / 2048.f) + 1e-5f);
  u16x8 o;
#pragma unroll
  for (int i = 0; i < 8; ++i) {
    float t = v[i] * rstd * g[tid * 8 + i] + bta[tid * 8 + i];
    o[i] = f2bf(gelu(t));
  }
  *(u16x8*)(out + (size_t)row * 2048 + tid * 8) = o;
}

// io += gelu(LN(in)*g+b), rows of 1024, in bf16, io fp32
__global__ __launch_bounds__(256) void k_final(
    const unsigned short* __restrict__ in, const float* __restrict__ g,
    const float* __restrict__ bta, float* __restrict__ io) {
  __shared__ float red[4];
  const int row = blockIdx.x, tid = threadIdx.x;
  const u16x4 iv = *(const u16x4*)(in + (size_t)row * 1024 + tid * 4);
  float v[4];
  float s = 0.f;
#pragma unroll
  for (int i = 0; i < 4; ++i) { v[i] = bf2f(iv[i]); s += v[i]; }
  s = blk_sum(s, red, tid, 4);
  const float mean = s * (1.f / 1024.f);
  float sq = 0.f;
#pragma unroll
  for (int i = 0; i < 4; ++i) { v[i] -= mean; sq += v[i] * v[i]; }
  sq = blk_sum(sq, red, tid, 4);
  const float rstd = rsqrtf(sq * (1.f / 1024.f) + 1e-5f);
  const f32x4 gv = *(const f32x4*)(g + tid * 4);
  const f32x4 bv = *(const f32x4*)(bta + tid * 4);
  f32x4 xi = *(const f32x4*)(io + (size_t)row * 1024 + tid * 4);
#pragma unroll
  for (int i = 0; i < 4; ++i)
    xi[i] += gelu(v[i] * rstd * gv[i] + bv[i]);
  *(f32x4*)(io + (size_t)row * 1024 + tid * 4) = xi;
}

// ---------------- GEMM: C_bf16[M][N] = A_bf16[M][K] @ Bt_bf16[N][K] + bias ----------------
__global__ __launch_bounds__(256) void k_gemm(
    const unsigned short* __restrict__ A, const unsigned short* __restrict__ Bt,
    const float* __restrict__ bias, unsigned short* __restrict__ C,
    int M, int N, int K) {
  __shared__ __align__(16) unsigned short As[128 * 64];
  __shared__ __align__(16) unsigned short Bs[128 * 64];
  const int tid = threadIdx.x;
  const int w = tid >> 6, l = tid & 63;
  const int m0 = blockIdx.y * 128, n0 = blockIdx.x * 128;
  const int wr = (w >> 1) * 64, wc = (w & 1) * 64;
  const f32x4 z4 = {0.f, 0.f, 0.f, 0.f};
  f32x4 acc[4][4];
#pragma unroll
  for (int i = 0; i < 4; ++i)
#pragma unroll
    for (int j = 0; j < 4; ++j) acc[i][j] = z4;

  const int srow = l >> 3, scol = (l & 7) * 8;
  for (int kt = 0; kt < K; kt += 64) {
#pragma unroll
    for (int i = 0; i < 4; ++i) {
      const int u = i * 4 + w;
      const int row = u * 8 + srow;
      gld16(A + (size_t)(m0 + row) * K + kt + scol, As + u * 512 + l * 8);
      gld16(Bt + (size_t)(n0 + row) * K + kt + scol, Bs + u * 512 + l * 8);
    }
    __syncthreads();
#pragma unroll
    for (int ks = 0; ks < 2; ++ks) {
      const int kb = ks * 32 + (l >> 4) * 8;
      s16x8 a[4], b[4];
#pragma unroll
      for (int m = 0; m < 4; ++m)
        a[m] = *(const s16x8*)(As + (wr + m * 16 + (l & 15)) * 64 + kb);
#pragma unroll
      for (int n = 0; n < 4; ++n)
        b[n] = *(const s16x8*)(Bs + (wc + n * 16 + (l & 15)) * 64 + kb);
#pragma unroll
      for (int m = 0; m < 4; ++m)
#pragma unroll
        for (int n = 0; n < 4; ++n)
          acc[m][n] = __builtin_amdgcn_mfma_f32_16x16x32_bf16(a[m], b[n], acc[m][n], 0, 0, 0);
    }
    __syncthreads();
  }
  const int rbase = m0 + wr + ((l >> 4) << 2);
  const int cbase = n0 + wc + (l & 15);
#pragma unroll
  for (int m = 0; m < 4; ++m) {
#pragma unroll
    for (int n = 0; n < 4; ++n) {
      const int c = cbase + n * 16;
      const float bb = bias[c];
#pragma unroll
      for (int r = 0; r < 4; ++r) {
        const int rr = rbase + m * 16 + r;
        C[(size_t)rr * N + c] = f2bf(acc[m][n][r] + bb);
      }
    }
  }
}

// ---------------- attention ----------------
__device__ __forceinline__ int swz(int r, int c) {
  return r * 64 + (c ^ ((r & 7) << 3));
}
__device__ __forceinline__ int vswz(int d, int k) {
  return d * 64 + (k ^ ((((d & 7) ^ ((d >> 3) & 7))) << 3));
}

__global__ __launch_bounds__(256) void k_attn(
    const unsigned short* __restrict__ qkv, unsigned short* __restrict__ O) {
  const int S = 1024;
  const int bid = blockIdx.x;
  const int qt = bid & 15;
  const int h = (bid >> 4) & 15;
  const int b = bid >> 8;
  const int tid = threadIdx.x, w = tid >> 6, l = tid & 63;

  __shared__ __align__(16) unsigned short Qs[64 * 64];
  __shared__ __align__(16) unsigned short Ks[64 * 64];
  __shared__ __align__(16) unsigned short Vt[64 * 64];
  __shared__ __align__(16) unsigned short Ps[4][16 * 64];

  const size_t rs = 3072;
  const unsigned short* qb = qkv + (size_t)b * S * rs + h * 64;
  const unsigned short* kbp = qb + 1024;
  const unsigned short* vbp = qb + 2048;
  const int q0 = qt * 64;

  {
    const int r = tid >> 3, c8 = (tid & 7) * 8;
#pragma unroll
    for (int i = 0; i < 2; ++i) {
      const int rr = i * 32 + r;
      u16x8 v = *(const u16x8*)(qb + (size_t)(q0 + rr) * rs + c8);
      *(u16x8*)(Qs + swz(rr, c8)) = v;
    }
  }
  __syncthreads();
  s16x8 qa[2];
  {
    const int row = w * 16 + (l & 15);
#pragma unroll
    for (int kh = 0; kh < 2; ++kh)
      qa[kh] = *(const s16x8*)(Qs + swz(row, kh * 32 + (l >> 4) * 8));
  }

  const f32x4 z4 = {0.f, 0.f, 0.f, 0.f};
  f32x4 oacc[4];
#pragma unroll
  for (int i = 0; i < 4; ++i) oacc[i] = z4;
  float mrun[4], lrun[4];
#pragma unroll
  for (int r = 0; r < 4; ++r) { mrun[r] = -1e30f; lrun[r] = 0.f; }

  for (int kc = 0; kc < S / 64; ++kc) {
    __syncthreads();
    {
      const int r = tid >> 3, c8 = (tid & 7) * 8;
#pragma unroll
      for (int i = 0; i < 2; ++i) {
        const int rr = i * 32 + r;
        u16x8 v = *(const u16x8*)(kbp + (size_t)(kc * 64 + rr) * rs + c8);
        *(u16x8*)(Ks + swz(rr, c8)) = v;
      }
#pragma unroll
      for (int i = 0; i < 2; ++i) {
        const int key = i * 32 + r;
        u16x8 v = *(const u16x8*)(vbp + (size_t)(kc * 64 + key) * rs + c8);
#pragma unroll
        for (int j = 0; j < 8; ++j) Vt[vswz(c8 + j, key)] = v[j];
      }
    }
    __syncthreads();

    f32x4 sacc[4];
#pragma unroll
    for (int t = 0; t < 4; ++t) {
      sacc[t] = z4;
#pragma unroll
      for (int kh = 0; kh < 2; ++kh) {
        s16x8 kf = *(const s16x8*)(Ks + swz(t * 16 + (l & 15), kh * 32 + (l >> 4) * 8));
        sacc[t] = __builtin_amdgcn_mfma_f32_16x16x32_bf16(qa[kh], kf, sacc[t], 0, 0, 0);
      }
    }

    float rmax[4];
#pragma unroll
    for (int r = 0; r < 4; ++r) {
      float m = sacc[0][r] * 0.125f;
#pragma unroll
      for (int t = 1; t < 4; ++t) m = fmaxf(m, sacc[t][r] * 0.125f);
#pragma unroll
      for (int msk = 8; msk >= 1; msk >>= 1) m = fmaxf(m, __shfl_xor(m, msk));
      rmax[r] = m;
    }
    float sc[4], nm[4], psum[4];
#pragma unroll
    for (int r = 0; r < 4; ++r) {
      nm[r] = fmaxf(mrun[r], rmax[r]);
      sc[r] = __expf(mrun[r] - nm[r]);
      mrun[r] = nm[r];
      psum[r] = 0.f;
    }
#pragma unroll
    for (int t = 0; t < 4; ++t) {
#pragma unroll
      for (int r = 0; r < 4; ++r) {
        float p = __expf(sacc[t][r] * 0.125f - nm[r]);
        psum[r] += p;
        const int prow = ((l >> 4) << 2) + r;
        Ps[w][swz(prow, t * 16 + (l & 15))] = f2bf(p);
      }
    }
#pragma unroll
    for (int r = 0; r < 4; ++r) {
      float s = psum[r];
#pragma unroll
      for (int msk = 8; msk >= 1; msk >>= 1) s += __shfl_xor(s, msk);
      lrun[r] = lrun[r] * sc[r] + s;
#pragma unroll
      for (int dg = 0; dg < 4; ++dg) oacc[dg][r] *= sc[r];
    }

    s16x8 pa[2];
#pragma unroll
    for (int kh = 0; kh < 2; ++kh)
      pa[kh] = *(const s16x8*)(Ps[w] + swz(l & 15, kh * 32 + (l >> 4) * 8));
#pragma unroll
    for (int dg = 0; dg < 4; ++dg) {
#pragma unroll
      for (int kh = 0; kh < 2; ++kh) {
        s16x8 vf = *(const s16x8*)(Vt + vswz(dg * 16 + (l & 15), kh * 32 + (l >> 4) * 8));
        oacc[dg] = __builtin_amdgcn_mfma_f32_16x16x32_bf16(pa[kh], vf, oacc[dg], 0, 0, 0);
      }
    }
  }

  float inv[4];
#pragma unroll
  for (int r = 0; r < 4; ++r) inv[r] = 1.f / lrun[r];
#pragma unroll
  for (int dg = 0; dg < 4; ++dg) {
#pragma unroll
    for (int r = 0; r < 4; ++r) {
      const int row = q0 + w * 16 + ((l >> 4) << 2) + r;
      const int col = h * 64 + dg * 16 + (l & 15);
      O[(size_t)(b * S + row) * 1024 + col] = f2bf(oacc[dg][r] * inv[r]);
    }
  }
}

// ---------------- launcher ----------------
extern "C" void kernel_launch(void* const* d_in, const int* in_sizes, int n_in,
                              void* d_out, int out_size, void* d_ws, size_t ws_size,
                              hipStream_t stream) {
  const float* X = (const float*)d_in[0];
  const float* Wq = (const float*)d_in[1];
  const float* bq = (const float*)d_in[2];
  const float* Wk = (const float*)d_in[3];
  const float* bk = (const float*)d_in[4];
  const float* Wv = (const float*)d_in[5];
  const float* bv = (const float*)d_in[6];
  const float* pre_g = (const float*)d_in[7];
  const float* pre_b = (const float*)d_in[8];
  const float* post_g = (const float*)d_in[9];
  const float* post_b = (const float*)d_in[10];
  const float* W1 = (const float*)d_in[11];
  const float* b1 = (const float*)d_in[12];
  const float* ln1_g = (const float*)d_in[13];
  const float* ln1_b = (const float*)d_in[14];
  const float* W2 = (const float*)d_in[15];
  const float* b2 = (const float*)d_in[16];
  const float* ln2_g = (const float*)d_in[17];
  const float* ln2_b = (const float*)d_in[18];
  float* out = (float*)d_out;

  char* ws = (char*)d_ws;
  const size_t MB = (size_t)1 << 20;
  unsigned short* t_bf = (unsigned short*)(ws);            // 16MB  [0,32MB) region
  unsigned short* attn_o = (unsigned short*)(ws);          // 16MB  (after t dead)
  unsigned short* mlp1 = (unsigned short*)(ws);            // 32MB  (after attn_o dead)
  unsigned short* qkv = (unsigned short*)(ws + 32 * MB);   // 48MB  [32,80MB)
  unsigned short* h1 = (unsigned short*)(ws + 32 * MB);    // 32MB  (after qkv dead)
  unsigned short* mlp2 = (unsigned short*)(ws + 64 * MB);  // 16MB
  unsigned short* t2 = (unsigned short*)(ws + 80 * MB);    // 16MB
  unsigned short* Wqkvt = (unsigned short*)(ws + 96 * MB); // 6MB
  unsigned short* W1t = (unsigned short*)(ws + 102 * MB);  // 4MB
  unsigned short* W2t = (unsigned short*)(ws + 106 * MB);  // 4MB
  float* biasq = (float*)(ws + 110 * MB);                  // 12KB

  // weight prep
  k_transpose<<<4096, 256, 0, stream>>>(Wq, Wqkvt, 1024, 64, 1048576);
  k_transpose<<<4096, 256, 0, stream>>>(Wk, Wqkvt + 1048576, 1024, 64, 1048576);
  k_transpose<<<4096, 256, 0, stream>>>(Wv, Wqkvt + 2097152, 1024, 64, 1048576);
  k_transpose<<<8192, 256, 0, stream>>>(W1, W1t, 1024, 2048, 2097152);
  k_transpose<<<8192, 256, 0, stream>>>(W2, W2t, 2048, 1024, 2097152);
  k_bias3<<<12, 256, 0, stream>>>(bq, bk, bv, biasq);

  // pre-LN
  k_pre_ln<<<8192, 256, 0, stream>>>(X, pre_g, pre_b, t_bf);
  // QKV projection: [8192x1024]@[1024x3072]
  k_gemm<<<dim3(24, 64), 256, 0, stream>>>(t_bf, Wqkvt, biasq, qkv, 8192, 3072, 1024);
  // attention
  k_attn<<<2048, 256, 0, stream>>>(qkv, attn_o);
  // residual + post-LN (X1 stored in d_out)
  k_res_ln<<<8192, 256, 0, stream>>>(X, attn_o, post_g, post_b, out, t2);
  // MLP1: [8192x1024]@[1024x2048]
  k_gemm<<<dim3(16, 64), 256, 0, stream>>>(t2, W1t, b1, mlp1, 8192, 2048, 1024);
  k_ln_gelu<<<8192, 256, 0, stream>>>(mlp1, ln1_g, ln1_b, h1);
  // MLP2: [8192x2048]@[2048x1024]
  k_gemm<<<dim3(8, 64), 256, 0, stream>>>(h1, W2t, b2, mlp2, 8192, 1024, 2048);
  // final: out = X1 + gelu(LN(mlp2))
  k_final<<<8192, 256, 0, stream>>>(mlp2, ln2_g, ln2_b, out);
}